// Round 2
// baseline (1386.884 us; speedup 1.0000x reference)
//
#include <hip/hip_runtime.h>
#include <stdint.h>

// ---------- types ----------
typedef __bf16  bf16x8 __attribute__((ext_vector_type(8)));
typedef short   s16x8  __attribute__((ext_vector_type(8)));
typedef float   f32x4  __attribute__((ext_vector_type(4)));

__device__ inline short f2bf(float f) {
  union { float f; uint32_t u; } v; v.f = f;
  uint32_t r = v.u + 0x7FFFu + ((v.u >> 16) & 1u);   // RNE
  return (short)(r >> 16);
}

// B=4, H=W=D=16 -> N=4096 tokens/batch, C=512, GROUPS=32 (16 ch/group)
// flattened M = B*N = 16384

// ---------- GroupNorm stats: one block per (b,g), reduce 4096*16 elems ----------
__global__ __launch_bounds__(256) void gn_stats_k(const float* __restrict__ x,
                                                  float* __restrict__ mean,
                                                  float* __restrict__ rstd) {
  int bg = blockIdx.x;                  // b*32+g
  int b = bg >> 5, g = bg & 31;
  int tid = threadIdx.x;
  const float* base = x + (size_t)b * 4096 * 512 + g * 16;
  float s = 0.f, q = 0.f;
  for (int i = tid; i < 16384; i += 256) {     // 4096 tokens * 4 float4 chunks
    int n = i >> 2, sub = i & 3;
    float4 v = *(const float4*)(base + (size_t)n * 512 + sub * 4);
    s += v.x + v.y + v.z + v.w;
    q += v.x * v.x + v.y * v.y + v.z * v.z + v.w * v.w;
  }
  for (int off = 32; off > 0; off >>= 1) {
    s += __shfl_down(s, off, 64);
    q += __shfl_down(q, off, 64);
  }
  __shared__ float rs[4], rq[4];
  int w = tid >> 6;
  if ((tid & 63) == 0) { rs[w] = s; rq[w] = q; }
  __syncthreads();
  if (tid == 0) {
    float S = rs[0] + rs[1] + rs[2] + rs[3];
    float Q = rq[0] + rq[1] + rq[2] + rq[3];
    float m = S * (1.f / 65536.f);
    float var = Q * (1.f / 65536.f) - m * m;
    mean[bg] = m;
    rstd[bg] = rsqrtf(var + 1e-6f);
  }
}

// ---------- GN apply -> bf16 h ----------
__global__ __launch_bounds__(256) void gn_apply_k(const float* __restrict__ x,
                                                  const float* __restrict__ mean,
                                                  const float* __restrict__ rstd,
                                                  const float* __restrict__ sc,
                                                  const float* __restrict__ bi,
                                                  short* __restrict__ h) {
  size_t i4 = ((size_t)blockIdx.x * 256 + threadIdx.x) * 4;
  int c = (int)(i4 & 511);
  int tok = (int)(i4 >> 9);
  int b = tok >> 12;
  int bg = b * 32 + (c >> 4);
  float m = mean[bg], r = rstd[bg];
  float4 v = *(const float4*)(x + i4);
  float4 s = *(const float4*)(sc + c);
  float4 bb = *(const float4*)(bi + c);
  short4 o;
  o.x = f2bf((v.x - m) * r * s.x + bb.x);
  o.y = f2bf((v.y - m) * r * s.y + bb.y);
  o.z = f2bf((v.z - m) * r * s.z + bb.z);
  o.w = f2bf((v.w - m) * r * s.w + bb.w);
  *(short4*)(h + i4) = o;
}

// ---------- weights -> bf16, transposed: wt[widx][j][c] = w[c][j] ----------
__global__ __launch_bounds__(256) void wconv_k(const float* __restrict__ wq,
                                               const float* __restrict__ wk,
                                               const float* __restrict__ wv,
                                               const float* __restrict__ wp,
                                               short* __restrict__ wt) {
  int i = blockIdx.x * 256 + threadIdx.x;          // 4 * 512 * 512
  int widx = i >> 18, rem = i & 262143;
  int c = rem >> 9, j = rem & 511;                 // read coalesced over j
  const float* w = widx == 0 ? wq : widx == 1 ? wk : widx == 2 ? wv : wp;
  wt[(size_t)widx * 262144 + (size_t)j * 512 + c] = f2bf(w[(size_t)c * 512 + j]);
}

// ---------- GEMM: C[m][n] = sum_k A[m][k] * Bt[n][k], M=16384 N=512 K=512 ----------
// tiles 128x128, BK=32, 4 waves each 64x64 (4x4 mfma 16x16x32), global_load_lds w=16.
// mode 0: out bf16 row-major (+bias)      [Q, K]
// mode 1: out bf16 transposed per-batch: vt[b][c][t] (+bias)   [V]
// mode 2: out fp32 = x + acc + bias        [final projection]
__global__ __launch_bounds__(256) void gemm_k(const short* __restrict__ A,
                                              const short* __restrict__ Bt,
                                              const float* __restrict__ bias,
                                              const float* __restrict__ xres,
                                              short* __restrict__ outb,
                                              float* __restrict__ outf, int mode) {
  __shared__ __attribute__((aligned(16))) short As[128 * 32];
  __shared__ __attribute__((aligned(16))) short Bs[128 * 32];
  int tid = threadIdx.x;
  int w = tid >> 6, lane = tid & 63, quad = lane >> 4, mrow = lane & 15;
  int wm = w >> 1, wn = w & 1;
  int m0 = blockIdx.x * 128, n0 = blockIdx.y * 128;

  const f32x4 fz = {0.f, 0.f, 0.f, 0.f};
  f32x4 acc[4][4];
#pragma unroll
  for (int i = 0; i < 4; i++)
#pragma unroll
    for (int j = 0; j < 4; j++) acc[i][j] = fz;

  int srow = tid >> 2;            // 0..63, 4 threads x 16B per 64B row of 32 bf16
  int scol = (tid & 3) * 8;

  for (int k0 = 0; k0 < 512; k0 += 32) {
    __syncthreads();
#pragma unroll
    for (int i = 0; i < 2; i++) {
      const short* ga = A + (size_t)(m0 + i * 64 + srow) * 512 + k0 + scol;
      const short* gb = Bt + (size_t)(n0 + i * 64 + srow) * 512 + k0 + scol;
      char* la = (char*)As + i * 4096 + w * 1024;   // wave-uniform base; HW adds lane*16
      char* lb = (char*)Bs + i * 4096 + w * 1024;
      __builtin_amdgcn_global_load_lds((__attribute__((address_space(1))) void*)ga,
                                       (__attribute__((address_space(3))) void*)la, 16, 0, 0);
      __builtin_amdgcn_global_load_lds((__attribute__((address_space(1))) void*)gb,
                                       (__attribute__((address_space(3))) void*)lb, 16, 0, 0);
    }
    __syncthreads();
    bf16x8 af[4], bfv[4];
#pragma unroll
    for (int mi = 0; mi < 4; mi++)
      af[mi] = *(const bf16x8*)&As[(wm * 64 + mi * 16 + mrow) * 32 + quad * 8];
#pragma unroll
    for (int ni = 0; ni < 4; ni++)
      bfv[ni] = *(const bf16x8*)&Bs[(wn * 64 + ni * 16 + mrow) * 32 + quad * 8];
#pragma unroll
    for (int mi = 0; mi < 4; mi++)
#pragma unroll
      for (int ni = 0; ni < 4; ni++)
        acc[mi][ni] = __builtin_amdgcn_mfma_f32_16x16x32_bf16(af[mi], bfv[ni], acc[mi][ni], 0, 0, 0);
  }

#pragma unroll
  for (int mi = 0; mi < 4; mi++)
#pragma unroll
    for (int ni = 0; ni < 4; ni++) {
      int col = n0 + wn * 64 + ni * 16 + mrow;   // C/D: col = lane&15
      float bv = bias[col];
#pragma unroll
      for (int r = 0; r < 4; r++) {
        int row = m0 + wm * 64 + mi * 16 + quad * 4 + r;   // row = quad*4 + reg
        float val = acc[mi][ni][r] + bv;
        if (mode == 0) {
          outb[(size_t)row * 512 + col] = f2bf(val);
        } else if (mode == 1) {
          int b = row >> 12, t = row & 4095;
          outb[(size_t)b * (512 * 4096) + (size_t)col * 4096 + t] = f2bf(val);
        } else {
          size_t idx = (size_t)row * 512 + col;
          outf[idx] = xres[idx] + val;
        }
      }
    }
}

// ---------- flash attention: 16-query tile/block, 4 waves x 128 channels ----------
// Q,K: [b*4096 + t][c] bf16 row-major.  Vt: [b][c][t] bf16.  O: row-major bf16.
__global__ __launch_bounds__(256) void flash_k(const short* __restrict__ Q,
                                               const short* __restrict__ K,
                                               const short* __restrict__ Vt,
                                               short* __restrict__ O) {
  int b = blockIdx.y;
  int q0 = blockIdx.x * 16;
  int tid = threadIdx.x;
  int w = tid >> 6, lane = tid & 63, quad = lane >> 4, m = lane & 15;

  __shared__ float part[4 * 528];   // [wave][16][33] padded
  __shared__ float S[528];          // [16][33] padded
  __shared__ float mL[16], lL[16], aL[16];

  const size_t batch_off = (size_t)b * 4096 * 512;
  const float scale = 0.044194173824159216f;   // 512^-0.5

  // Q fragments for this wave's 128 channels (A-layout: m=lane&15, k=quad*8+j)
  bf16x8 qf[4];
#pragma unroll
  for (int ks = 0; ks < 4; ks++)
    qf[ks] = *(const bf16x8*)&Q[batch_off + (size_t)(q0 + m) * 512 + w * 128 + ks * 32 + quad * 8];

  const f32x4 fz = {0.f, 0.f, 0.f, 0.f};
  f32x4 oacc[8];
#pragma unroll
  for (int i = 0; i < 8; i++) oacc[i] = fz;

  if (tid < 16) { mL[tid] = -1e30f; lL[tid] = 0.f; }
  __syncthreads();

  for (int t0 = 0; t0 < 4096; t0 += 32) {
    // 1) partial S (16q x 32t) over this wave's 128 channels
    f32x4 sacc[2]; sacc[0] = fz; sacc[1] = fz;
#pragma unroll
    for (int tn = 0; tn < 2; tn++)
#pragma unroll
      for (int ks = 0; ks < 4; ks++) {
        bf16x8 kf = *(const bf16x8*)&K[batch_off + (size_t)(t0 + tn * 16 + m) * 512 +
                                       w * 128 + ks * 32 + quad * 8];
        sacc[tn] = __builtin_amdgcn_mfma_f32_16x16x32_bf16(qf[ks], kf, sacc[tn], 0, 0, 0);
      }
    // 2) partials -> LDS (C-layout: col=lane&15 -> t, row=quad*4+r -> q)
#pragma unroll
    for (int tn = 0; tn < 2; tn++)
#pragma unroll
      for (int r = 0; r < 4; r++)
        part[w * 528 + (quad * 4 + r) * 33 + tn * 16 + m] = sacc[tn][r];
    __syncthreads();
    // 3) cross-wave reduce + logit scale
    for (int e = tid; e < 512; e += 256) {
      int row = e >> 5, col = e & 31;
      float v = part[row * 33 + col] + part[528 + row * 33 + col] +
                part[1056 + row * 33 + col] + part[1584 + row * 33 + col];
      S[row * 33 + col] = v * scale;
    }
    __syncthreads();
    // 4) online softmax, one row per lane (threads 0..15)
    if (tid < 16) {
      int row = tid;
      float mo = mL[row];
      float mx = mo;
      for (int j = 0; j < 32; j++) mx = fmaxf(mx, S[row * 33 + j]);
      float al = __expf(mo - mx);
      float sum = 0.f;
      for (int j = 0; j < 32; j++) {
        float p = __expf(S[row * 33 + j] - mx);
        S[row * 33 + j] = p;
        sum += p;
      }
      mL[row] = mx;
      lL[row] = lL[row] * al + sum;
      aL[row] = al;
    }
    __syncthreads();
    // 5) rescale O accumulators
    float al[4];
#pragma unroll
    for (int r = 0; r < 4; r++) al[r] = aL[quad * 4 + r];
#pragma unroll
    for (int i = 0; i < 8; i++)
#pragma unroll
      for (int r = 0; r < 4; r++) oacc[i][r] *= al[r];
    // 6) P fragment (A-layout: m=lane&15, k=quad*8+j), fp32->bf16
    s16x8 pfs;
#pragma unroll
    for (int j = 0; j < 8; j++) pfs[j] = f2bf(S[m * 33 + quad * 8 + j]);
    bf16x8 pf = __builtin_bit_cast(bf16x8, pfs);
    // 7) O += P @ V  (B-frag from Vt: n=lane&15 -> c, k=quad*8+j -> t, contiguous)
#pragma unroll
    for (int ct = 0; ct < 8; ct++) {
      bf16x8 vf = *(const bf16x8*)&Vt[batch_off + (size_t)(w * 128 + ct * 16 + m) * 4096 +
                                      t0 + quad * 8];
      oacc[ct] = __builtin_amdgcn_mfma_f32_16x16x32_bf16(pf, vf, oacc[ct], 0, 0, 0);
    }
    // no barrier needed: next iter's part-writes are fenced by the step-3 barrier
  }
  // epilogue: O /= l, store bf16 row-major
  float inv[4];
#pragma unroll
  for (int r = 0; r < 4; r++) inv[r] = 1.f / lL[quad * 4 + r];
#pragma unroll
  for (int ct = 0; ct < 8; ct++)
#pragma unroll
    for (int r = 0; r < 4; r++) {
      int row = q0 + quad * 4 + r;
      int col = w * 128 + ct * 16 + m;
      O[batch_off + (size_t)row * 512 + col] = f2bf(oacc[ct][r] * inv[r]);
    }
}

extern "C" void kernel_launch(void* const* d_in, const int* in_sizes, int n_in,
                              void* d_out, int out_size, void* d_ws, size_t ws_size,
                              hipStream_t stream) {
  const float* x  = (const float*)d_in[0];
  const float* gs = (const float*)d_in[1];
  const float* gb = (const float*)d_in[2];
  const float* wq = (const float*)d_in[3];
  const float* bq = (const float*)d_in[4];
  const float* wk = (const float*)d_in[5];
  const float* bk = (const float*)d_in[6];
  const float* wv = (const float*)d_in[7];
  const float* bv = (const float*)d_in[8];
  const float* wp = (const float*)d_in[9];
  const float* bp = (const float*)d_in[10];
  float* out = (float*)d_out;

  // ---- workspace layout (total 35,652,608 B ≈ 34 MB; was 86 MB -> OOB) ----
  // Q and K live in d_out (33.55 MB scratch until the final projection
  // overwrites it); Ob aliases h (h is dead after the V GEMM).
  char* ws = (char*)d_ws;
  float* mean = (float*)ws;                               // 128 f
  float* rstd = (float*)(ws + 512);                       // 128 f
  short* h    = (short*)(ws + 1024);                      // 16384*512 bf16 (16.78 MB)
  short* wt   = (short*)(ws + 1024 + 16777216);           // 4*512*512 bf16 (2 MB)
  short* Vt   = (short*)(ws + 1024 + 16777216 + 2097152); // [b][c][t] bf16 (16.78 MB)
  short* Qb   = (short*)d_out;                            // 16.78 MB in d_out
  short* Kb   = Qb + 8388608;                             // 16.78 MB in d_out
  short* Ob   = h;                                        // alias: h dead after V GEMM

  gn_stats_k<<<128, 256, 0, stream>>>(x, mean, rstd);
  gn_apply_k<<<8192, 256, 0, stream>>>(x, mean, rstd, gs, gb, h);
  wconv_k<<<4096, 256, 0, stream>>>(wq, wk, wv, wp, wt);
  dim3 gg(128, 4);
  gemm_k<<<gg, 256, 0, stream>>>(h, wt,          bq, nullptr, Qb, nullptr, 0);
  gemm_k<<<gg, 256, 0, stream>>>(h, wt + 262144, bk, nullptr, Kb, nullptr, 0);
  gemm_k<<<gg, 256, 0, stream>>>(h, wt + 524288, bv, nullptr, Vt, nullptr, 1);
  dim3 fg(256, 4);
  flash_k<<<fg, 256, 0, stream>>>(Qb, Kb, Vt, Ob);
  // final projection reads Ob (=h space), x, wt_p; writes d_out (overwrites Q/K)
  gemm_k<<<gg, 256, 0, stream>>>(Ob, wt + 786432, bp, x, nullptr, out, 2);
}

// Round 3
// 1335.729 us; speedup vs baseline: 1.0383x; 1.0383x over previous
//
#include <hip/hip_runtime.h>
#include <stdint.h>

// ---------- types ----------
typedef __bf16  bf16x8 __attribute__((ext_vector_type(8)));
typedef short   s16x8  __attribute__((ext_vector_type(8)));
typedef float   f32x4  __attribute__((ext_vector_type(4)));

__device__ inline short f2bf(float f) {
  union { float f; uint32_t u; } v; v.f = f;
  uint32_t r = v.u + 0x7FFFu + ((v.u >> 16) & 1u);   // RNE
  return (short)(r >> 16);
}

// B=4, H=W=D=16 -> N=4096 tokens/batch, C=512, GROUPS=32 (16 ch/group)
// flattened M = B*N = 16384

// ---------- GroupNorm stats: one block per (b,g), reduce 4096*16 elems ----------
__global__ __launch_bounds__(256) void gn_stats_k(const float* __restrict__ x,
                                                  float* __restrict__ mean,
                                                  float* __restrict__ rstd) {
  int bg = blockIdx.x;                  // b*32+g
  int b = bg >> 5, g = bg & 31;
  int tid = threadIdx.x;
  const float* base = x + (size_t)b * 4096 * 512 + g * 16;
  float s = 0.f, q = 0.f;
  for (int i = tid; i < 16384; i += 256) {     // 4096 tokens * 4 float4 chunks
    int n = i >> 2, sub = i & 3;
    float4 v = *(const float4*)(base + (size_t)n * 512 + sub * 4);
    s += v.x + v.y + v.z + v.w;
    q += v.x * v.x + v.y * v.y + v.z * v.z + v.w * v.w;
  }
  for (int off = 32; off > 0; off >>= 1) {
    s += __shfl_down(s, off, 64);
    q += __shfl_down(q, off, 64);
  }
  __shared__ float rs[4], rq[4];
  int w = tid >> 6;
  if ((tid & 63) == 0) { rs[w] = s; rq[w] = q; }
  __syncthreads();
  if (tid == 0) {
    float S = rs[0] + rs[1] + rs[2] + rs[3];
    float Q = rq[0] + rq[1] + rq[2] + rq[3];
    float m = S * (1.f / 65536.f);
    float var = Q * (1.f / 65536.f) - m * m;
    mean[bg] = m;
    rstd[bg] = rsqrtf(var + 1e-6f);
  }
}

// ---------- GN apply -> bf16 h ----------
__global__ __launch_bounds__(256) void gn_apply_k(const float* __restrict__ x,
                                                  const float* __restrict__ mean,
                                                  const float* __restrict__ rstd,
                                                  const float* __restrict__ sc,
                                                  const float* __restrict__ bi,
                                                  short* __restrict__ h) {
  size_t i4 = ((size_t)blockIdx.x * 256 + threadIdx.x) * 4;
  int c = (int)(i4 & 511);
  int tok = (int)(i4 >> 9);
  int b = tok >> 12;
  int bg = b * 32 + (c >> 4);
  float m = mean[bg], r = rstd[bg];
  float4 v = *(const float4*)(x + i4);
  float4 s = *(const float4*)(sc + c);
  float4 bb = *(const float4*)(bi + c);
  short4 o;
  o.x = f2bf((v.x - m) * r * s.x + bb.x);
  o.y = f2bf((v.y - m) * r * s.y + bb.y);
  o.z = f2bf((v.z - m) * r * s.z + bb.z);
  o.w = f2bf((v.w - m) * r * s.w + bb.w);
  *(short4*)(h + i4) = o;
}

// ---------- weights -> bf16, transposed: wt[widx][j][c] = w[c][j] ----------
__global__ __launch_bounds__(256) void wconv_k(const float* __restrict__ wq,
                                               const float* __restrict__ wk,
                                               const float* __restrict__ wv,
                                               const float* __restrict__ wp,
                                               short* __restrict__ wt) {
  int i = blockIdx.x * 256 + threadIdx.x;          // 4 * 512 * 512
  int widx = i >> 18, rem = i & 262143;
  int c = rem >> 9, j = rem & 511;                 // read coalesced over j
  const float* w = widx == 0 ? wq : widx == 1 ? wk : widx == 2 ? wv : wp;
  wt[(size_t)widx * 262144 + (size_t)j * 512 + c] = f2bf(w[(size_t)c * 512 + j]);
}

// ---------- GEMM: C[m][n] = sum_k A[m][k] * Bt[n][k], M=16384 N=512 K=512 ----------
// tiles 128x128, BK=32, 4 waves each 64x64 (4x4 mfma 16x16x32), global_load_lds w=16.
// mode 0: out bf16 row-major (+bias)      [Q, K]
// mode 1: out bf16 transposed per-batch: vt[b][c][t] (+bias)   [V]
// mode 2: out fp32 = x + acc + bias        [final projection]
__global__ __launch_bounds__(256) void gemm_k(const short* __restrict__ A,
                                              const short* __restrict__ Bt,
                                              const float* __restrict__ bias,
                                              const float* __restrict__ xres,
                                              short* __restrict__ outb,
                                              float* __restrict__ outf, int mode) {
  __shared__ __attribute__((aligned(16))) short As[128 * 32];
  __shared__ __attribute__((aligned(16))) short Bs[128 * 32];
  int tid = threadIdx.x;
  int w = tid >> 6, lane = tid & 63, quad = lane >> 4, mrow = lane & 15;
  int wm = w >> 1, wn = w & 1;
  int m0 = blockIdx.x * 128, n0 = blockIdx.y * 128;

  const f32x4 fz = {0.f, 0.f, 0.f, 0.f};
  f32x4 acc[4][4];
#pragma unroll
  for (int i = 0; i < 4; i++)
#pragma unroll
    for (int j = 0; j < 4; j++) acc[i][j] = fz;

  int srow = tid >> 2;            // 0..63, 4 threads x 16B per 64B row of 32 bf16
  int scol = (tid & 3) * 8;

  for (int k0 = 0; k0 < 512; k0 += 32) {
    __syncthreads();
#pragma unroll
    for (int i = 0; i < 2; i++) {
      const short* ga = A + (size_t)(m0 + i * 64 + srow) * 512 + k0 + scol;
      const short* gb = Bt + (size_t)(n0 + i * 64 + srow) * 512 + k0 + scol;
      char* la = (char*)As + i * 4096 + w * 1024;   // wave-uniform base; HW adds lane*16
      char* lb = (char*)Bs + i * 4096 + w * 1024;
      __builtin_amdgcn_global_load_lds((__attribute__((address_space(1))) void*)ga,
                                       (__attribute__((address_space(3))) void*)la, 16, 0, 0);
      __builtin_amdgcn_global_load_lds((__attribute__((address_space(1))) void*)gb,
                                       (__attribute__((address_space(3))) void*)lb, 16, 0, 0);
    }
    __syncthreads();
    bf16x8 af[4], bfv[4];
#pragma unroll
    for (int mi = 0; mi < 4; mi++)
      af[mi] = *(const bf16x8*)&As[(wm * 64 + mi * 16 + mrow) * 32 + quad * 8];
#pragma unroll
    for (int ni = 0; ni < 4; ni++)
      bfv[ni] = *(const bf16x8*)&Bs[(wn * 64 + ni * 16 + mrow) * 32 + quad * 8];
#pragma unroll
    for (int mi = 0; mi < 4; mi++)
#pragma unroll
      for (int ni = 0; ni < 4; ni++)
        acc[mi][ni] = __builtin_amdgcn_mfma_f32_16x16x32_bf16(af[mi], bfv[ni], acc[mi][ni], 0, 0, 0);
  }

#pragma unroll
  for (int mi = 0; mi < 4; mi++)
#pragma unroll
    for (int ni = 0; ni < 4; ni++) {
      int col = n0 + wn * 64 + ni * 16 + mrow;   // C/D: col = lane&15
      float bv = bias[col];
#pragma unroll
      for (int r = 0; r < 4; r++) {
        int row = m0 + wm * 64 + mi * 16 + quad * 4 + r;   // row = quad*4 + reg
        float val = acc[mi][ni][r] + bv;
        if (mode == 0) {
          outb[(size_t)row * 512 + col] = f2bf(val);
        } else if (mode == 1) {
          int b = row >> 12, t = row & 4095;
          outb[(size_t)b * (512 * 4096) + (size_t)col * 4096 + t] = f2bf(val);
        } else {
          size_t idx = (size_t)row * 512 + col;
          outf[idx] = xres[idx] + val;
        }
      }
    }
}

// ---------- flash attention: 16-query tile/block, 4 waves x 128 channels ----------
// Q,K: [b*4096 + t][c] bf16 row-major.  Vt: [b][c][t] bf16.  O: row-major bf16.
// Softmax is fully parallel: 512 S-elements spread over 512 thread-slots,
// row max/sum via __shfl_xor over the 32-lane row group, exp2 with log2(e)
// folded into the logit scale. Per-row online state (m,l,alpha) is owned by
// the col==0 lane; each row belongs to exactly one wave -> no cross-wave race.
__global__ __launch_bounds__(256) void flash_k(const short* __restrict__ Q,
                                               const short* __restrict__ K,
                                               const short* __restrict__ Vt,
                                               short* __restrict__ O) {
  int b = blockIdx.y;
  int q0 = blockIdx.x * 16;
  int tid = threadIdx.x;
  int w = tid >> 6, lane = tid & 63, quad = lane >> 4, m = lane & 15;

  __shared__ float part[4 * 528];   // [wave][16][33] padded
  __shared__ float S[528];          // [16][33] padded
  __shared__ float mL[16], lL[16], aL[16];

  const size_t batch_off = (size_t)b * 4096 * 512;
  const float scale2 = 0.06375879f;   // 512^-0.5 * log2(e)

  // Q fragments for this wave's 128 channels (A-layout: m=lane&15, k=quad*8+j)
  bf16x8 qf[4];
#pragma unroll
  for (int ks = 0; ks < 4; ks++)
    qf[ks] = *(const bf16x8*)&Q[batch_off + (size_t)(q0 + m) * 512 + w * 128 + ks * 32 + quad * 8];

  const f32x4 fz = {0.f, 0.f, 0.f, 0.f};
  f32x4 oacc[8];
#pragma unroll
  for (int i = 0; i < 8; i++) oacc[i] = fz;

  if (tid < 16) { mL[tid] = -1e30f; lL[tid] = 0.f; }
  __syncthreads();

  for (int t0 = 0; t0 < 4096; t0 += 32) {
    // 1) partial S (16q x 32t) over this wave's 128 channels
    f32x4 sacc[2]; sacc[0] = fz; sacc[1] = fz;
#pragma unroll
    for (int tn = 0; tn < 2; tn++)
#pragma unroll
      for (int ks = 0; ks < 4; ks++) {
        bf16x8 kf = *(const bf16x8*)&K[batch_off + (size_t)(t0 + tn * 16 + m) * 512 +
                                       w * 128 + ks * 32 + quad * 8];
        sacc[tn] = __builtin_amdgcn_mfma_f32_16x16x32_bf16(qf[ks], kf, sacc[tn], 0, 0, 0);
      }
    // 2) partials -> LDS (C-layout: col=lane&15 -> t, row=quad*4+r -> q)
#pragma unroll
    for (int tn = 0; tn < 2; tn++)
#pragma unroll
      for (int r = 0; r < 4; r++)
        part[w * 528 + (quad * 4 + r) * 33 + tn * 16 + m] = sacc[tn][r];
    __syncthreads();
    // 3+4) fused cross-wave reduce + PARALLEL online softmax (2 rows/thread-slot)
#pragma unroll
    for (int ee = 0; ee < 2; ee++) {
      int e = tid + ee * 256;
      int row = e >> 5, col = e & 31;
      float v = part[row * 33 + col] + part[528 + row * 33 + col] +
                part[1056 + row * 33 + col] + part[1584 + row * 33 + col];
      v *= scale2;                                   // logit scale, log2e folded
      float mx = v;
      mx = fmaxf(mx, __shfl_xor(mx, 16, 64));
      mx = fmaxf(mx, __shfl_xor(mx, 8, 64));
      mx = fmaxf(mx, __shfl_xor(mx, 4, 64));
      mx = fmaxf(mx, __shfl_xor(mx, 2, 64));
      mx = fmaxf(mx, __shfl_xor(mx, 1, 64));
      float mo = mL[row];                            // broadcast LDS read
      float mn = fmaxf(mo, mx);
      float p = exp2f(v - mn);                       // single v_exp_f32
      float s = p;
      s += __shfl_xor(s, 16, 64);
      s += __shfl_xor(s, 8, 64);
      s += __shfl_xor(s, 4, 64);
      s += __shfl_xor(s, 2, 64);
      s += __shfl_xor(s, 1, 64);
      S[row * 33 + col] = p;
      if (col == 0) {                                // row owner updates state
        float al = exp2f(mo - mn);
        aL[row] = al;
        lL[row] = lL[row] * al + s;
        mL[row] = mn;
      }
    }
    __syncthreads();
    // 5) rescale O accumulators
    float al[4];
#pragma unroll
    for (int r = 0; r < 4; r++) al[r] = aL[quad * 4 + r];
#pragma unroll
    for (int i = 0; i < 8; i++)
#pragma unroll
      for (int r = 0; r < 4; r++) oacc[i][r] *= al[r];
    // 6) P fragment (A-layout: m=lane&15, k=quad*8+j), fp32->bf16
    s16x8 pfs;
#pragma unroll
    for (int j = 0; j < 8; j++) pfs[j] = f2bf(S[m * 33 + quad * 8 + j]);
    bf16x8 pf = __builtin_bit_cast(bf16x8, pfs);
    // 7) O += P @ V  (B-frag from Vt: n=lane&15 -> c, k=quad*8+j -> t, contiguous)
#pragma unroll
    for (int ct = 0; ct < 8; ct++) {
      bf16x8 vf = *(const bf16x8*)&Vt[batch_off + (size_t)(w * 128 + ct * 16 + m) * 4096 +
                                      t0 + quad * 8];
      oacc[ct] = __builtin_amdgcn_mfma_f32_16x16x32_bf16(pf, vf, oacc[ct], 0, 0, 0);
    }
    // next iter's part-writes are fenced by the step-3 barrier of this iter
  }
  // epilogue: O /= l, store bf16 row-major
  float inv[4];
#pragma unroll
  for (int r = 0; r < 4; r++) inv[r] = 1.f / lL[quad * 4 + r];
#pragma unroll
  for (int ct = 0; ct < 8; ct++)
#pragma unroll
    for (int r = 0; r < 4; r++) {
      int row = q0 + quad * 4 + r;
      int col = w * 128 + ct * 16 + m;
      O[batch_off + (size_t)row * 512 + col] = f2bf(oacc[ct][r] * inv[r]);
    }
}

extern "C" void kernel_launch(void* const* d_in, const int* in_sizes, int n_in,
                              void* d_out, int out_size, void* d_ws, size_t ws_size,
                              hipStream_t stream) {
  const float* x  = (const float*)d_in[0];
  const float* gs = (const float*)d_in[1];
  const float* gb = (const float*)d_in[2];
  const float* wq = (const float*)d_in[3];
  const float* bq = (const float*)d_in[4];
  const float* wk = (const float*)d_in[5];
  const float* bk = (const float*)d_in[6];
  const float* wv = (const float*)d_in[7];
  const float* bv = (const float*)d_in[8];
  const float* wp = (const float*)d_in[9];
  const float* bp = (const float*)d_in[10];
  float* out = (float*)d_out;

  // ---- workspace layout (total ~34 MB; Q/K live in d_out until final GEMM) ----
  char* ws = (char*)d_ws;
  float* mean = (float*)ws;                               // 128 f
  float* rstd = (float*)(ws + 512);                       // 128 f
  short* h    = (short*)(ws + 1024);                      // 16384*512 bf16 (16.78 MB)
  short* wt   = (short*)(ws + 1024 + 16777216);           // 4*512*512 bf16 (2 MB)
  short* Vt   = (short*)(ws + 1024 + 16777216 + 2097152); // [b][c][t] bf16 (16.78 MB)
  short* Qb   = (short*)d_out;                            // 16.78 MB in d_out
  short* Kb   = Qb + 8388608;                             // 16.78 MB in d_out
  short* Ob   = h;                                        // alias: h dead after V GEMM

  gn_stats_k<<<128, 256, 0, stream>>>(x, mean, rstd);
  gn_apply_k<<<8192, 256, 0, stream>>>(x, mean, rstd, gs, gb, h);
  wconv_k<<<4096, 256, 0, stream>>>(wq, wk, wv, wp, wt);
  dim3 gg(128, 4);
  gemm_k<<<gg, 256, 0, stream>>>(h, wt,          bq, nullptr, Qb, nullptr, 0);
  gemm_k<<<gg, 256, 0, stream>>>(h, wt + 262144, bk, nullptr, Kb, nullptr, 0);
  gemm_k<<<gg, 256, 0, stream>>>(h, wt + 524288, bv, nullptr, Vt, nullptr, 1);
  dim3 fg(256, 4);
  flash_k<<<fg, 256, 0, stream>>>(Qb, Kb, Vt, Ob);
  // final projection reads Ob (=h space), x, wt_p; writes d_out (overwrites Q/K)
  gemm_k<<<gg, 256, 0, stream>>>(Ob, wt + 786432, bp, x, nullptr, out, 2);
}

// Round 4
// 980.401 us; speedup vs baseline: 1.4146x; 1.3624x over previous
//
#include <hip/hip_runtime.h>
#include <stdint.h>

// ---------- types ----------
typedef __bf16  bf16x8 __attribute__((ext_vector_type(8)));
typedef short   s16x8  __attribute__((ext_vector_type(8)));
typedef float   f32x4  __attribute__((ext_vector_type(4)));

__device__ inline short f2bf(float f) {
  union { float f; uint32_t u; } v; v.f = f;
  uint32_t r = v.u + 0x7FFFu + ((v.u >> 16) & 1u);   // RNE
  return (short)(r >> 16);
}

// B=4, H=W=D=16 -> N=4096 tokens/batch, C=512, GROUPS=32 (16 ch/group)
// flattened M = B*N = 16384

// ---------- GroupNorm stats: one block per (b,g), reduce 4096*16 elems ----------
__global__ __launch_bounds__(256) void gn_stats_k(const float* __restrict__ x,
                                                  float* __restrict__ mean,
                                                  float* __restrict__ rstd) {
  int bg = blockIdx.x;                  // b*32+g
  int b = bg >> 5, g = bg & 31;
  int tid = threadIdx.x;
  const float* base = x + (size_t)b * 4096 * 512 + g * 16;
  float s = 0.f, q = 0.f;
  for (int i = tid; i < 16384; i += 256) {     // 4096 tokens * 4 float4 chunks
    int n = i >> 2, sub = i & 3;
    float4 v = *(const float4*)(base + (size_t)n * 512 + sub * 4);
    s += v.x + v.y + v.z + v.w;
    q += v.x * v.x + v.y * v.y + v.z * v.z + v.w * v.w;
  }
  for (int off = 32; off > 0; off >>= 1) {
    s += __shfl_down(s, off, 64);
    q += __shfl_down(q, off, 64);
  }
  __shared__ float rs[4], rq[4];
  int w = tid >> 6;
  if ((tid & 63) == 0) { rs[w] = s; rq[w] = q; }
  __syncthreads();
  if (tid == 0) {
    float S = rs[0] + rs[1] + rs[2] + rs[3];
    float Q = rq[0] + rq[1] + rq[2] + rq[3];
    float m = S * (1.f / 65536.f);
    float var = Q * (1.f / 65536.f) - m * m;
    mean[bg] = m;
    rstd[bg] = rsqrtf(var + 1e-6f);
  }
}

// ---------- GN apply -> bf16 h ----------
__global__ __launch_bounds__(256) void gn_apply_k(const float* __restrict__ x,
                                                  const float* __restrict__ mean,
                                                  const float* __restrict__ rstd,
                                                  const float* __restrict__ sc,
                                                  const float* __restrict__ bi,
                                                  short* __restrict__ h) {
  size_t i4 = ((size_t)blockIdx.x * 256 + threadIdx.x) * 4;
  int c = (int)(i4 & 511);
  int tok = (int)(i4 >> 9);
  int b = tok >> 12;
  int bg = b * 32 + (c >> 4);
  float m = mean[bg], r = rstd[bg];
  float4 v = *(const float4*)(x + i4);
  float4 s = *(const float4*)(sc + c);
  float4 bb = *(const float4*)(bi + c);
  short4 o;
  o.x = f2bf((v.x - m) * r * s.x + bb.x);
  o.y = f2bf((v.y - m) * r * s.y + bb.y);
  o.z = f2bf((v.z - m) * r * s.z + bb.z);
  o.w = f2bf((v.w - m) * r * s.w + bb.w);
  *(short4*)(h + i4) = o;
}

// ---------- weights -> bf16, transposed: wt[widx][j][c] = w[c][j] ----------
__global__ __launch_bounds__(256) void wconv_k(const float* __restrict__ wq,
                                               const float* __restrict__ wk,
                                               const float* __restrict__ wv,
                                               const float* __restrict__ wp,
                                               short* __restrict__ wt) {
  int i = blockIdx.x * 256 + threadIdx.x;          // 4 * 512 * 512
  int widx = i >> 18, rem = i & 262143;
  int c = rem >> 9, j = rem & 511;                 // read coalesced over j
  const float* w = widx == 0 ? wq : widx == 1 ? wk : widx == 2 ? wv : wp;
  wt[(size_t)widx * 262144 + (size_t)j * 512 + c] = f2bf(w[(size_t)c * 512 + j]);
}

// ---------- GEMM: C[m][n] = sum_k A[m][k] * Bt[n][k], M=16384 N=512 K=512 ----------
__global__ __launch_bounds__(256) void gemm_k(const short* __restrict__ A,
                                              const short* __restrict__ Bt,
                                              const float* __restrict__ bias,
                                              const float* __restrict__ xres,
                                              short* __restrict__ outb,
                                              float* __restrict__ outf, int mode) {
  __shared__ __attribute__((aligned(16))) short As[128 * 32];
  __shared__ __attribute__((aligned(16))) short Bs[128 * 32];
  int tid = threadIdx.x;
  int w = tid >> 6, lane = tid & 63, quad = lane >> 4, mrow = lane & 15;
  int wm = w >> 1, wn = w & 1;
  int m0 = blockIdx.x * 128, n0 = blockIdx.y * 128;

  const f32x4 fz = {0.f, 0.f, 0.f, 0.f};
  f32x4 acc[4][4];
#pragma unroll
  for (int i = 0; i < 4; i++)
#pragma unroll
    for (int j = 0; j < 4; j++) acc[i][j] = fz;

  int srow = tid >> 2;            // 0..63, 4 threads x 16B per 64B row of 32 bf16
  int scol = (tid & 3) * 8;

  for (int k0 = 0; k0 < 512; k0 += 32) {
    __syncthreads();
#pragma unroll
    for (int i = 0; i < 2; i++) {
      const short* ga = A + (size_t)(m0 + i * 64 + srow) * 512 + k0 + scol;
      const short* gb = Bt + (size_t)(n0 + i * 64 + srow) * 512 + k0 + scol;
      char* la = (char*)As + i * 4096 + w * 1024;   // wave-uniform base; HW adds lane*16
      char* lb = (char*)Bs + i * 4096 + w * 1024;
      __builtin_amdgcn_global_load_lds((__attribute__((address_space(1))) void*)ga,
                                       (__attribute__((address_space(3))) void*)la, 16, 0, 0);
      __builtin_amdgcn_global_load_lds((__attribute__((address_space(1))) void*)gb,
                                       (__attribute__((address_space(3))) void*)lb, 16, 0, 0);
    }
    __syncthreads();
    bf16x8 af[4], bfv[4];
#pragma unroll
    for (int mi = 0; mi < 4; mi++)
      af[mi] = *(const bf16x8*)&As[(wm * 64 + mi * 16 + mrow) * 32 + quad * 8];
#pragma unroll
    for (int ni = 0; ni < 4; ni++)
      bfv[ni] = *(const bf16x8*)&Bs[(wn * 64 + ni * 16 + mrow) * 32 + quad * 8];
#pragma unroll
    for (int mi = 0; mi < 4; mi++)
#pragma unroll
      for (int ni = 0; ni < 4; ni++)
        acc[mi][ni] = __builtin_amdgcn_mfma_f32_16x16x32_bf16(af[mi], bfv[ni], acc[mi][ni], 0, 0, 0);
  }

#pragma unroll
  for (int mi = 0; mi < 4; mi++)
#pragma unroll
    for (int ni = 0; ni < 4; ni++) {
      int col = n0 + wn * 64 + ni * 16 + mrow;   // C/D: col = lane&15
      float bv = bias[col];
#pragma unroll
      for (int r = 0; r < 4; r++) {
        int row = m0 + wm * 64 + mi * 16 + quad * 4 + r;   // row = quad*4 + reg
        float val = acc[mi][ni][r] + bv;
        if (mode == 0) {
          outb[(size_t)row * 512 + col] = f2bf(val);
        } else if (mode == 1) {
          int b = row >> 12, t = row & 4095;
          outb[(size_t)b * (512 * 4096) + (size_t)col * 4096 + t] = f2bf(val);
        } else {
          size_t idx = (size_t)row * 512 + col;
          outf[idx] = xres[idx] + val;
        }
      }
    }
}

// ---------- flash attention v2: wave-autonomous, K-tile double-buffered ----------
// Block = 64 queries (4 waves x 16q); each wave: all 512 channels of its 16 q.
// S computed TRANSPOSED: mfma(A=kf, B=qf) -> row(quad*4+r)=key, col(lane&15)=query.
// Softmax per-lane (8 keys/lane for query m) + shfl_xor(16,32) across quads;
// m/l state in registers. P -> A-frag via 16 in-register shuffles (no LDS).
// K-tile (32 keys x 512 ch = 32 KB) double-buffered in LDS via global_load_lds.
// LDS layout Ks[buf][ks=ch/8][key32][8ch] -> frag reads conflict-free.
// V read direct from Vt[b][c][t] (coalesced 16B B-frags, independent of softmax).
// ONE barrier per 32-key iteration.
__global__ __launch_bounds__(256, 1) void flash_k(const short* __restrict__ Q,
                                                  const short* __restrict__ K,
                                                  const short* __restrict__ Vt,
                                                  short* __restrict__ O) {
  __shared__ __attribute__((aligned(16))) short Ks[2][16384];   // 64 KB exactly
  int b = blockIdx.y;
  int q0 = blockIdx.x * 64;
  int tid = threadIdx.x;
  int w = tid >> 6, lane = tid & 63, quad = lane >> 4, m = lane & 15;
  const size_t batch_off = (size_t)b * 4096 * 512;
  const float scale2 = 0.06375872f;   // 512^-0.5 * log2(e)

  // Q fragments (B-operand: n=query=lane&15, k=ch=quad*8+j), 16 k-steps = all 512 ch
  bf16x8 qf[16];
#pragma unroll
  for (int s = 0; s < 16; s++)
    qf[s] = *(const bf16x8*)&Q[batch_off + (size_t)(q0 + w * 16 + m) * 512 + s * 32 + quad * 8];

  const f32x4 fz = {0.f, 0.f, 0.f, 0.f};
  f32x4 oacc[32];
#pragma unroll
  for (int i = 0; i < 32; i++) oacc[i] = fz;
  float mrun = -1e30f, lrun = 0.f;   // per-lane state for query m (replicated /quad)

  // ---- stage K-tile for iter 0 into buf 0 ----
  // wave w stages ks-pairs p = w*8+i (ks = ch/8, 64 values, 32 pairs).
  // lane l -> key = l&31, ks = ksb + (l>>5); dst = base + l*16B (HW adds lane*16).
#pragma unroll
  for (int i = 0; i < 8; i++) {
    int ksb = w * 16 + i * 2;
    const short* gk = K + batch_off + (size_t)(lane & 31) * 512 + (size_t)(ksb + (lane >> 5)) * 8;
    __builtin_amdgcn_global_load_lds((__attribute__((address_space(1))) void*)gk,
                                     (__attribute__((address_space(3))) void*)&Ks[0][ksb * 256],
                                     16, 0, 0);
  }

  for (int it = 0; it < 128; ++it) {
    int t0 = it * 32;
    int buf = it & 1;
    __syncthreads();   // staging of buf visible (vmcnt(0) drain) + all waves done with buf^1
    if (it < 127) {
      int t1 = t0 + 32;
#pragma unroll
      for (int i = 0; i < 8; i++) {
        int ksb = w * 16 + i * 2;
        const short* gk = K + batch_off + (size_t)(t1 + (lane & 31)) * 512 +
                          (size_t)(ksb + (lane >> 5)) * 8;
        __builtin_amdgcn_global_load_lds((__attribute__((address_space(1))) void*)gk,
                                         (__attribute__((address_space(3))) void*)&Ks[buf ^ 1][ksb * 256],
                                         16, 0, 0);
      }
    }
    // ---- QK^T (transposed): sacc_tn[row=key16][col=query] ----
    f32x4 s0 = fz, s1 = fz;
#pragma unroll
    for (int s = 0; s < 16; s++) {
      bf16x8 k0 = *(const bf16x8*)&Ks[buf][((s * 4 + quad) * 32 + m) * 8];
      bf16x8 k1 = *(const bf16x8*)&Ks[buf][((s * 4 + quad) * 32 + 16 + m) * 8];
      s0 = __builtin_amdgcn_mfma_f32_16x16x32_bf16(k0, qf[s], s0, 0, 0, 0);
      s1 = __builtin_amdgcn_mfma_f32_16x16x32_bf16(k1, qf[s], s1, 0, 0, 0);
    }
    // ---- per-lane online softmax for query m (keys tn*16 + quad*4 + r) ----
    float v0[4], v1[4];
    float mx = -1e30f;
#pragma unroll
    for (int r = 0; r < 4; r++) {
      v0[r] = s0[r] * scale2;
      v1[r] = s1[r] * scale2;
      mx = fmaxf(mx, fmaxf(v0[r], v1[r]));
    }
    mx = fmaxf(mx, __shfl_xor(mx, 16, 64));
    mx = fmaxf(mx, __shfl_xor(mx, 32, 64));
    float mn = fmaxf(mrun, mx);
    float alpha = exp2f(mrun - mn);
    mrun = mn;
    float p0[4], p1[4];
    float sum = 0.f;
#pragma unroll
    for (int r = 0; r < 4; r++) {
      p0[r] = exp2f(v0[r] - mn);
      p1[r] = exp2f(v1[r] - mn);
      sum += p0[r] + p1[r];
    }
    sum += __shfl_xor(sum, 16, 64);
    sum += __shfl_xor(sum, 32, 64);
    lrun = lrun * alpha + sum;
    // ---- rescale O (skip when no row max changed: alpha==1 exactly) ----
    if (__any(alpha != 1.0f)) {
      float al[4];
#pragma unroll
      for (int r = 0; r < 4; r++) al[r] = __shfl(alpha, quad * 4 + r, 64);
#pragma unroll
      for (int i = 0; i < 32; i++)
#pragma unroll
        for (int r = 0; r < 4; r++) oacc[i][r] *= al[r];
    }
    // ---- P -> A-frag (A[m=query=lane&15][k=key=quad*8+j]) via shuffles ----
    // dst (qd,m) elem j needs P[q=m][key=qd*8+j] = p_{qd>>1}[j&3] from lane
    // ((qd&1)*2 + (j>>2))<<4 | m.
    s16x8 pfs;
#pragma unroll
    for (int j = 0; j < 8; j++) {
      int src = ((((quad & 1) * 2 + (j >> 2)) << 4) | m);
      float a0 = __shfl(p0[j & 3], src, 64);
      float a1 = __shfl(p1[j & 3], src, 64);
      pfs[j] = f2bf(quad < 2 ? a0 : a1);
    }
    bf16x8 pf = __builtin_bit_cast(bf16x8, pfs);
    // ---- O += P @ V  (B-frag direct from Vt: n=ch=lane&15, k=key=quad*8+j) ----
#pragma unroll
    for (int ct = 0; ct < 32; ct++) {
      bf16x8 vf = *(const bf16x8*)&Vt[batch_off + (size_t)(ct * 16 + m) * 4096 + t0 + quad * 8];
      oacc[ct] = __builtin_amdgcn_mfma_f32_16x16x32_bf16(pf, vf, oacc[ct], 0, 0, 0);
    }
  }
  // ---- epilogue: O /= l, store bf16 row-major ----
  float invl = 1.f / lrun;
  float inv[4];
#pragma unroll
  for (int r = 0; r < 4; r++) inv[r] = __shfl(invl, quad * 4 + r, 64);
#pragma unroll
  for (int ct = 0; ct < 32; ct++)
#pragma unroll
    for (int r = 0; r < 4; r++) {
      int row = q0 + w * 16 + quad * 4 + r;
      int col = ct * 16 + m;
      O[batch_off + (size_t)row * 512 + col] = f2bf(oacc[ct][r] * inv[r]);
    }
}

extern "C" void kernel_launch(void* const* d_in, const int* in_sizes, int n_in,
                              void* d_out, int out_size, void* d_ws, size_t ws_size,
                              hipStream_t stream) {
  const float* x  = (const float*)d_in[0];
  const float* gs = (const float*)d_in[1];
  const float* gb = (const float*)d_in[2];
  const float* wq = (const float*)d_in[3];
  const float* bq = (const float*)d_in[4];
  const float* wk = (const float*)d_in[5];
  const float* bk = (const float*)d_in[6];
  const float* wv = (const float*)d_in[7];
  const float* bv = (const float*)d_in[8];
  const float* wp = (const float*)d_in[9];
  const float* bp = (const float*)d_in[10];
  float* out = (float*)d_out;

  // ---- workspace layout (total ~34 MB; Q/K live in d_out until final GEMM) ----
  char* ws = (char*)d_ws;
  float* mean = (float*)ws;                               // 128 f
  float* rstd = (float*)(ws + 512);                       // 128 f
  short* h    = (short*)(ws + 1024);                      // 16384*512 bf16 (16.78 MB)
  short* wt   = (short*)(ws + 1024 + 16777216);           // 4*512*512 bf16 (2 MB)
  short* Vt   = (short*)(ws + 1024 + 16777216 + 2097152); // [b][c][t] bf16 (16.78 MB)
  short* Qb   = (short*)d_out;                            // 16.78 MB in d_out
  short* Kb   = Qb + 8388608;                             // 16.78 MB in d_out
  short* Ob   = h;                                        // alias: h dead after V GEMM

  gn_stats_k<<<128, 256, 0, stream>>>(x, mean, rstd);
  gn_apply_k<<<8192, 256, 0, stream>>>(x, mean, rstd, gs, gb, h);
  wconv_k<<<4096, 256, 0, stream>>>(wq, wk, wv, wp, wt);
  dim3 gg(128, 4);
  gemm_k<<<gg, 256, 0, stream>>>(h, wt,          bq, nullptr, Qb, nullptr, 0);
  gemm_k<<<gg, 256, 0, stream>>>(h, wt + 262144, bk, nullptr, Kb, nullptr, 0);
  gemm_k<<<gg, 256, 0, stream>>>(h, wt + 524288, bv, nullptr, Vt, nullptr, 1);
  dim3 fg(64, 4);
  flash_k<<<fg, 256, 0, stream>>>(Qb, Kb, Vt, Ob);
  // final projection reads Ob (=h space), x, wt_p; writes d_out (overwrites Q/K)
  gemm_k<<<gg, 256, 0, stream>>>(Ob, wt + 786432, bp, x, nullptr, out, 2);
}

// Round 5
// 848.581 us; speedup vs baseline: 1.6344x; 1.1553x over previous
//
#include <hip/hip_runtime.h>
#include <stdint.h>

// ---------- types ----------
typedef __bf16  bf16x8 __attribute__((ext_vector_type(8)));
typedef short   s16x8  __attribute__((ext_vector_type(8)));
typedef float   f32x4  __attribute__((ext_vector_type(4)));

__device__ inline short f2bf(float f) {
  union { float f; uint32_t u; } v; v.f = f;
  uint32_t r = v.u + 0x7FFFu + ((v.u >> 16) & 1u);   // RNE
  return (short)(r >> 16);
}

// B=4, H=W=D=16 -> N=4096 tokens/batch, C=512, GROUPS=32 (16 ch/group)
// flattened M = B*N = 16384

// ---------- GroupNorm stats: one block per (b,g), reduce 4096*16 elems ----------
__global__ __launch_bounds__(256) void gn_stats_k(const float* __restrict__ x,
                                                  float* __restrict__ mean,
                                                  float* __restrict__ rstd) {
  int bg = blockIdx.x;                  // b*32+g
  int b = bg >> 5, g = bg & 31;
  int tid = threadIdx.x;
  const float* base = x + (size_t)b * 4096 * 512 + g * 16;
  float s = 0.f, q = 0.f;
  for (int i = tid; i < 16384; i += 256) {     // 4096 tokens * 4 float4 chunks
    int n = i >> 2, sub = i & 3;
    float4 v = *(const float4*)(base + (size_t)n * 512 + sub * 4);
    s += v.x + v.y + v.z + v.w;
    q += v.x * v.x + v.y * v.y + v.z * v.z + v.w * v.w;
  }
  for (int off = 32; off > 0; off >>= 1) {
    s += __shfl_down(s, off, 64);
    q += __shfl_down(q, off, 64);
  }
  __shared__ float rs[4], rq[4];
  int w = tid >> 6;
  if ((tid & 63) == 0) { rs[w] = s; rq[w] = q; }
  __syncthreads();
  if (tid == 0) {
    float S = rs[0] + rs[1] + rs[2] + rs[3];
    float Q = rq[0] + rq[1] + rq[2] + rq[3];
    float m = S * (1.f / 65536.f);
    float var = Q * (1.f / 65536.f) - m * m;
    mean[bg] = m;
    rstd[bg] = rsqrtf(var + 1e-6f);
  }
}

// ---------- GN apply -> bf16 h ----------
__global__ __launch_bounds__(256) void gn_apply_k(const float* __restrict__ x,
                                                  const float* __restrict__ mean,
                                                  const float* __restrict__ rstd,
                                                  const float* __restrict__ sc,
                                                  const float* __restrict__ bi,
                                                  short* __restrict__ h) {
  size_t i4 = ((size_t)blockIdx.x * 256 + threadIdx.x) * 4;
  int c = (int)(i4 & 511);
  int tok = (int)(i4 >> 9);
  int b = tok >> 12;
  int bg = b * 32 + (c >> 4);
  float m = mean[bg], r = rstd[bg];
  float4 v = *(const float4*)(x + i4);
  float4 s = *(const float4*)(sc + c);
  float4 bb = *(const float4*)(bi + c);
  short4 o;
  o.x = f2bf((v.x - m) * r * s.x + bb.x);
  o.y = f2bf((v.y - m) * r * s.y + bb.y);
  o.z = f2bf((v.z - m) * r * s.z + bb.z);
  o.w = f2bf((v.w - m) * r * s.w + bb.w);
  *(short4*)(h + i4) = o;
}

// ---------- weights -> bf16, transposed: wt[widx][j][c] = w[c][j] ----------
__global__ __launch_bounds__(256) void wconv_k(const float* __restrict__ wq,
                                               const float* __restrict__ wk,
                                               const float* __restrict__ wv,
                                               const float* __restrict__ wp,
                                               short* __restrict__ wt) {
  int i = blockIdx.x * 256 + threadIdx.x;          // 4 * 512 * 512
  int widx = i >> 18, rem = i & 262143;
  int c = rem >> 9, j = rem & 511;                 // read coalesced over j
  const float* w = widx == 0 ? wq : widx == 1 ? wk : widx == 2 ? wv : wp;
  wt[(size_t)widx * 262144 + (size_t)j * 512 + c] = f2bf(w[(size_t)c * 512 + j]);
}

// ---------- GEMM: C[m][n] = sum_k A[m][k] * Bt[n][k], M=16384 N=512 K=512 ----------
__global__ __launch_bounds__(256) void gemm_k(const short* __restrict__ A,
                                              const short* __restrict__ Bt,
                                              const float* __restrict__ bias,
                                              const float* __restrict__ xres,
                                              short* __restrict__ outb,
                                              float* __restrict__ outf, int mode) {
  __shared__ __attribute__((aligned(16))) short As[128 * 32];
  __shared__ __attribute__((aligned(16))) short Bs[128 * 32];
  int tid = threadIdx.x;
  int w = tid >> 6, lane = tid & 63, quad = lane >> 4, mrow = lane & 15;
  int wm = w >> 1, wn = w & 1;
  int m0 = blockIdx.x * 128, n0 = blockIdx.y * 128;

  const f32x4 fz = {0.f, 0.f, 0.f, 0.f};
  f32x4 acc[4][4];
#pragma unroll
  for (int i = 0; i < 4; i++)
#pragma unroll
    for (int j = 0; j < 4; j++) acc[i][j] = fz;

  int srow = tid >> 2;            // 0..63, 4 threads x 16B per 64B row of 32 bf16
  int scol = (tid & 3) * 8;

  for (int k0 = 0; k0 < 512; k0 += 32) {
    __syncthreads();
#pragma unroll
    for (int i = 0; i < 2; i++) {
      const short* ga = A + (size_t)(m0 + i * 64 + srow) * 512 + k0 + scol;
      const short* gb = Bt + (size_t)(n0 + i * 64 + srow) * 512 + k0 + scol;
      char* la = (char*)As + i * 4096 + w * 1024;   // wave-uniform base; HW adds lane*16
      char* lb = (char*)Bs + i * 4096 + w * 1024;
      __builtin_amdgcn_global_load_lds((__attribute__((address_space(1))) void*)ga,
                                       (__attribute__((address_space(3))) void*)la, 16, 0, 0);
      __builtin_amdgcn_global_load_lds((__attribute__((address_space(1))) void*)gb,
                                       (__attribute__((address_space(3))) void*)lb, 16, 0, 0);
    }
    __syncthreads();
    bf16x8 af[4], bfv[4];
#pragma unroll
    for (int mi = 0; mi < 4; mi++)
      af[mi] = *(const bf16x8*)&As[(wm * 64 + mi * 16 + mrow) * 32 + quad * 8];
#pragma unroll
    for (int ni = 0; ni < 4; ni++)
      bfv[ni] = *(const bf16x8*)&Bs[(wn * 64 + ni * 16 + mrow) * 32 + quad * 8];
#pragma unroll
    for (int mi = 0; mi < 4; mi++)
#pragma unroll
      for (int ni = 0; ni < 4; ni++)
        acc[mi][ni] = __builtin_amdgcn_mfma_f32_16x16x32_bf16(af[mi], bfv[ni], acc[mi][ni], 0, 0, 0);
  }

#pragma unroll
  for (int mi = 0; mi < 4; mi++)
#pragma unroll
    for (int ni = 0; ni < 4; ni++) {
      int col = n0 + wn * 64 + ni * 16 + mrow;   // C/D: col = lane&15
      float bv = bias[col];
#pragma unroll
      for (int r = 0; r < 4; r++) {
        int row = m0 + wm * 64 + mi * 16 + quad * 4 + r;   // row = quad*4 + reg
        float val = acc[mi][ni][r] + bv;
        if (mode == 0) {
          outb[(size_t)row * 512 + col] = f2bf(val);
        } else if (mode == 1) {
          int b = row >> 12, t = row & 4095;
          outb[(size_t)b * (512 * 4096) + (size_t)col * 4096 + t] = f2bf(val);
        } else {
          size_t idx = (size_t)row * 512 + col;
          outf[idx] = xres[idx] + val;
        }
      }
    }
}

// ---------- flash attention v3: wave-autonomous + intra-wave pipelining ----------
// Block = 64 queries (4 waves x 16q), wave-autonomous (no cross-wave reduce).
// v3 changes vs v2 (occupancy is grid-capped at 1 wave/SIMD, so buy ILP):
//  (1) all 32 V B-frag loads hoisted to iteration top (addresses depend only on
//      t0) -> ~full-iteration distance-to-use hides L2/L3 latency. ~380 VGPRs,
//      fine at 1 wave/SIMD.
//  (2) QK^T split into 4 accumulator chains (8-deep) to overlap MFMA latency.
//  (3) blockIdx swizzle: batch b -> XCD pair {2b,2b+1} (linear%8 heuristic) so
//      Vt (4 MB/batch) stays L2-resident on its XCD pair.
__global__ __launch_bounds__(256, 1) void flash_k(const short* __restrict__ Q,
                                                  const short* __restrict__ K,
                                                  const short* __restrict__ Vt,
                                                  short* __restrict__ O) {
  __shared__ __attribute__((aligned(16))) short Ks[2][16384];   // 64 KB exactly
  int L = blockIdx.x;
  int b = (L & 7) >> 1;                    // batch -> XCD pair (L%8 round-robin)
  int q0 = (((L >> 3) << 1) | (L & 1)) * 64;
  int tid = threadIdx.x;
  int w = tid >> 6, lane = tid & 63, quad = lane >> 4, m = lane & 15;
  const size_t batch_off = (size_t)b * 4096 * 512;
  const float scale2 = 0.06375872f;   // 512^-0.5 * log2(e)

  // Q fragments (B-operand: n=query=lane&15, k=ch=quad*8+j), 16 k-steps = 512 ch
  bf16x8 qf[16];
#pragma unroll
  for (int s = 0; s < 16; s++)
    qf[s] = *(const bf16x8*)&Q[batch_off + (size_t)(q0 + w * 16 + m) * 512 + s * 32 + quad * 8];

  const f32x4 fz = {0.f, 0.f, 0.f, 0.f};
  f32x4 oacc[32];
#pragma unroll
  for (int i = 0; i < 32; i++) oacc[i] = fz;
  float mrun = -1e30f, lrun = 0.f;   // per-lane state for query m (replicated /quad)

  // ---- stage K-tile for iter 0 into buf 0 ----
#pragma unroll
  for (int i = 0; i < 8; i++) {
    int ksb = w * 16 + i * 2;
    const short* gk = K + batch_off + (size_t)(lane & 31) * 512 + (size_t)(ksb + (lane >> 5)) * 8;
    __builtin_amdgcn_global_load_lds((__attribute__((address_space(1))) void*)gk,
                                     (__attribute__((address_space(3))) void*)&Ks[0][ksb * 256],
                                     16, 0, 0);
  }

  for (int it = 0; it < 128; ++it) {
    int t0 = it * 32;
    int buf = it & 1;
    __syncthreads();   // staging of buf visible + all waves done with buf^1
    if (it < 127) {
      int t1 = t0 + 32;
#pragma unroll
      for (int i = 0; i < 8; i++) {
        int ksb = w * 16 + i * 2;
        const short* gk = K + batch_off + (size_t)(t1 + (lane & 31)) * 512 +
                          (size_t)(ksb + (lane >> 5)) * 8;
        __builtin_amdgcn_global_load_lds((__attribute__((address_space(1))) void*)gk,
                                         (__attribute__((address_space(3))) void*)&Ks[buf ^ 1][ksb * 256],
                                         16, 0, 0);
      }
    }
    // ---- V B-frag loads for THIS iter, hoisted: ~whole iter of latency slack ----
    bf16x8 vf[32];
#pragma unroll
    for (int ct = 0; ct < 32; ct++)
      vf[ct] = *(const bf16x8*)&Vt[batch_off + (size_t)(ct * 16 + m) * 4096 + t0 + quad * 8];
    // ---- QK^T (transposed): 4 chains of 8 to overlap MFMA latency ----
    f32x4 s0a = fz, s0b = fz, s1a = fz, s1b = fz;
#pragma unroll
    for (int s = 0; s < 16; s++) {
      bf16x8 k0 = *(const bf16x8*)&Ks[buf][((s * 4 + quad) * 32 + m) * 8];
      bf16x8 k1 = *(const bf16x8*)&Ks[buf][((s * 4 + quad) * 32 + 16 + m) * 8];
      if (s & 1) {
        s0b = __builtin_amdgcn_mfma_f32_16x16x32_bf16(k0, qf[s], s0b, 0, 0, 0);
        s1b = __builtin_amdgcn_mfma_f32_16x16x32_bf16(k1, qf[s], s1b, 0, 0, 0);
      } else {
        s0a = __builtin_amdgcn_mfma_f32_16x16x32_bf16(k0, qf[s], s0a, 0, 0, 0);
        s1a = __builtin_amdgcn_mfma_f32_16x16x32_bf16(k1, qf[s], s1a, 0, 0, 0);
      }
    }
    // ---- per-lane online softmax for query m (keys tn*16 + quad*4 + r) ----
    float v0[4], v1[4];
    float mx = -1e30f;
#pragma unroll
    for (int r = 0; r < 4; r++) {
      v0[r] = (s0a[r] + s0b[r]) * scale2;
      v1[r] = (s1a[r] + s1b[r]) * scale2;
      mx = fmaxf(mx, fmaxf(v0[r], v1[r]));
    }
    mx = fmaxf(mx, __shfl_xor(mx, 16, 64));
    mx = fmaxf(mx, __shfl_xor(mx, 32, 64));
    float mn = fmaxf(mrun, mx);
    float alpha = exp2f(mrun - mn);
    mrun = mn;
    float p0[4], p1[4];
    float sum = 0.f;
#pragma unroll
    for (int r = 0; r < 4; r++) {
      p0[r] = exp2f(v0[r] - mn);
      p1[r] = exp2f(v1[r] - mn);
      sum += p0[r] + p1[r];
    }
    sum += __shfl_xor(sum, 16, 64);
    sum += __shfl_xor(sum, 32, 64);
    lrun = lrun * alpha + sum;
    // ---- rescale O (skip when no row max changed: alpha==1 exactly) ----
    if (__any(alpha != 1.0f)) {
      float al[4];
#pragma unroll
      for (int r = 0; r < 4; r++) al[r] = __shfl(alpha, quad * 4 + r, 64);
#pragma unroll
      for (int i = 0; i < 32; i++)
#pragma unroll
        for (int r = 0; r < 4; r++) oacc[i][r] *= al[r];
    }
    // ---- P -> A-frag (A[m=query=lane&15][k=key=quad*8+j]) via shuffles ----
    s16x8 pfs;
#pragma unroll
    for (int j = 0; j < 8; j++) {
      int src = ((((quad & 1) * 2 + (j >> 2)) << 4) | m);
      float a0 = __shfl(p0[j & 3], src, 64);
      float a1 = __shfl(p1[j & 3], src, 64);
      pfs[j] = f2bf(quad < 2 ? a0 : a1);
    }
    bf16x8 pf = __builtin_bit_cast(bf16x8, pfs);
    // ---- O += P @ V  (vf prefetched at iter top; 32 independent accs) ----
#pragma unroll
    for (int ct = 0; ct < 32; ct++)
      oacc[ct] = __builtin_amdgcn_mfma_f32_16x16x32_bf16(pf, vf[ct], oacc[ct], 0, 0, 0);
  }
  // ---- epilogue: O /= l, store bf16 row-major ----
  float invl = 1.f / lrun;
  float inv[4];
#pragma unroll
  for (int r = 0; r < 4; r++) inv[r] = __shfl(invl, quad * 4 + r, 64);
#pragma unroll
  for (int ct = 0; ct < 32; ct++)
#pragma unroll
    for (int r = 0; r < 4; r++) {
      int row = q0 + w * 16 + quad * 4 + r;
      int col = ct * 16 + m;
      O[batch_off + (size_t)row * 512 + col] = f2bf(oacc[ct][r] * inv[r]);
    }
}

extern "C" void kernel_launch(void* const* d_in, const int* in_sizes, int n_in,
                              void* d_out, int out_size, void* d_ws, size_t ws_size,
                              hipStream_t stream) {
  const float* x  = (const float*)d_in[0];
  const float* gs = (const float*)d_in[1];
  const float* gb = (const float*)d_in[2];
  const float* wq = (const float*)d_in[3];
  const float* bq = (const float*)d_in[4];
  const float* wk = (const float*)d_in[5];
  const float* bk = (const float*)d_in[6];
  const float* wv = (const float*)d_in[7];
  const float* bv = (const float*)d_in[8];
  const float* wp = (const float*)d_in[9];
  const float* bp = (const float*)d_in[10];
  float* out = (float*)d_out;

  // ---- workspace layout (total ~34 MB; Q/K live in d_out until final GEMM) ----
  char* ws = (char*)d_ws;
  float* mean = (float*)ws;                               // 128 f
  float* rstd = (float*)(ws + 512);                       // 128 f
  short* h    = (short*)(ws + 1024);                      // 16384*512 bf16 (16.78 MB)
  short* wt   = (short*)(ws + 1024 + 16777216);           // 4*512*512 bf16 (2 MB)
  short* Vt   = (short*)(ws + 1024 + 16777216 + 2097152); // [b][c][t] bf16 (16.78 MB)
  short* Qb   = (short*)d_out;                            // 16.78 MB in d_out
  short* Kb   = Qb + 8388608;                             // 16.78 MB in d_out
  short* Ob   = h;                                        // alias: h dead after V GEMM

  gn_stats_k<<<128, 256, 0, stream>>>(x, mean, rstd);
  gn_apply_k<<<8192, 256, 0, stream>>>(x, mean, rstd, gs, gb, h);
  wconv_k<<<4096, 256, 0, stream>>>(wq, wk, wv, wp, wt);
  dim3 gg(128, 4);
  gemm_k<<<gg, 256, 0, stream>>>(h, wt,          bq, nullptr, Qb, nullptr, 0);
  gemm_k<<<gg, 256, 0, stream>>>(h, wt + 262144, bk, nullptr, Kb, nullptr, 0);
  gemm_k<<<gg, 256, 0, stream>>>(h, wt + 524288, bv, nullptr, Vt, nullptr, 1);
  flash_k<<<256, 256, 0, stream>>>(Qb, Kb, Vt, Ob);
  // final projection reads Ob (=h space), x, wt_p; writes d_out (overwrites Q/K)
  gemm_k<<<gg, 256, 0, stream>>>(Ob, wt + 786432, bp, x, nullptr, out, 2);
}